// Round 1
// 162.274 us; speedup vs baseline: 1.0102x; 1.0102x over previous
//
#include <hip/hip_runtime.h>
#include <math.h>

#define B_ 2
#define L_ 2048
#define H_ 16
#define E_ 64
#define D_ 64
#define DM_ 512
#define DH_ 256

typedef __bf16 bf16_t;
typedef bf16_t bf16x8_t __attribute__((ext_vector_type(8)));
typedef float f32x4_t __attribute__((ext_vector_type(4)));

// pack two floats to bf16x2 (round-up-at-halfway; 2 add + 1 perm)
__device__ __forceinline__ unsigned bpack(float hi, float lo) {
    unsigned uh = __float_as_uint(hi) + 0x8000u;
    unsigned ul = __float_as_uint(lo) + 0x8000u;
    return __builtin_amdgcn_perm(uh, ul, 0x07060302u);
}

__device__ __forceinline__ bf16_t to_bf16(float f) {
    union { float f; unsigned u; } x; x.f = f;
    unsigned r = (x.u + 0x7fffu + ((x.u >> 16) & 1u)) >> 16;
    union { unsigned short s; bf16_t b; } y; y.s = (unsigned short)r;
    return y.b;
}

// ---------------- w1 [512 k][256 n] f32 -> w1t [256 n][512 k] bf16 ------------
__global__ __launch_bounds__(256) void transpose_w1_kernel(
        const float* __restrict__ w1, bf16_t* __restrict__ w1t) {
    const int n = blockIdx.x;          // one output row per block
    const int t = threadIdx.x;
    #pragma unroll
    for (int u = 0; u < 2; ++u) {
        int k = t + u * 256;
        float v = w1[(size_t)k * DH_ + n];   // strided read (L2-shared lines)
        w1t[(size_t)n * DM_ + k] = to_bf16(v); // coalesced write
    }
}

// ---------------- MLP via MFMA: fused = relu(raw@w1+b1)@w2 + b2 --------------
// 256 blocks x 256 threads; block owns 16 rows, wave owns a 64-wide n-quarter.
__global__ __launch_bounds__(256) void mlp_kernel(
        const float* __restrict__ raw, const bf16_t* __restrict__ w1t,
        const float* __restrict__ b1, const float* __restrict__ w2,
        const float* __restrict__ b2, float* __restrict__ fused) {
    __shared__ bf16_t Rs[16][520];     // raw rows, bf16, padded stride
    __shared__ float part[4][16];
    const int t = threadIdx.x;
    const int m0 = blockIdx.x * 16;
    // stage 16 raw rows (16x512 f32) -> bf16 LDS
    #pragma unroll
    for (int u = 0; u < 8; ++u) {
        int idx = t + u * 256;
        int row = idx >> 7;            // 128 f32x4 per row
        int k = (idx & 127) << 2;
        f32x4_t v = *(const f32x4_t*)&raw[(size_t)(m0 + row) * DM_ + k];
        uint2 p;
        p.x = bpack(v[1], v[0]);
        p.y = bpack(v[3], v[2]);
        *(uint2*)&Rs[row][k] = p;
    }
    __syncthreads();
    const int wave = t >> 6;
    const int lane = t & 63;
    const int lrow = lane & 15;
    const int lgrp = lane >> 4;
    const int n0w = wave * 64;

    f32x4_t acc[4];
    #pragma unroll
    for (int nt = 0; nt < 4; ++nt) acc[nt] = (f32x4_t){0.f, 0.f, 0.f, 0.f};

    const bf16_t* wbase = w1t + (size_t)(n0w + lrow) * DM_ + lgrp * 8;
    #pragma unroll
    for (int s = 0; s < 16; ++s) {
        bf16x8_t a = *(const bf16x8_t*)&Rs[lrow][s * 32 + lgrp * 8];
        #pragma unroll
        for (int nt = 0; nt < 4; ++nt) {
            bf16x8_t b = *(const bf16x8_t*)(wbase + nt * 16 * DM_ + s * 32);
            acc[nt] = __builtin_amdgcn_mfma_f32_16x16x32_bf16(a, b, acc[nt], 0, 0, 0);
        }
    }
    // epilogue: relu + @w2, reduce over n
    float rowpart[4] = {0.f, 0.f, 0.f, 0.f};
    #pragma unroll
    for (int nt = 0; nt < 4; ++nt) {
        int n = n0w + nt * 16 + lrow;
        float b1v = b1[n];
        float w2v = w2[n];
        #pragma unroll
        for (int r = 0; r < 4; ++r) {
            float h = acc[nt][r] + b1v;
            h = h > 0.f ? h : 0.f;
            rowpart[r] += h * w2v;
        }
    }
    #pragma unroll
    for (int r = 0; r < 4; ++r) {
        float v = rowpart[r];
        v += __shfl_xor(v, 1);
        v += __shfl_xor(v, 2);
        v += __shfl_xor(v, 4);
        v += __shfl_xor(v, 8);
        if (lrow == 0) part[wave][lgrp * 4 + r] = v;
    }
    __syncthreads();
    if (t < 16)
        fused[m0 + t] = part[0][t] + part[1][t] + part[2][t] + part[3][t] + b2[0];
}

// ---------------- momentum ----------------------------------------------------
__global__ __launch_bounds__(256) void momentum_kernel(
        const float* __restrict__ fused, float* __restrict__ mom) {
    int i = blockIdx.x * 256 + threadIdx.x;
    if (i < B_ * L_) {
        int l = i & (L_ - 1);
        mom[i] = (l == 0) ? 0.f : fused[i] - fused[i - 1];
    }
}

// ---------------- flash attention, swapped-QK^T, lane-local P ----------------
// QK^T computed as mfma(K,Q) with K rows PERMUTED in LDS so each lane's 16
// S values land exactly in the PV A-fragment layout: zero P round-trip.
// Permutation: LDS row p(s) = s[1:0] | s[4:3]<<2 | s[2]<<4 | s[5]<<5, so that
// c-tile c, output row m holds s = 8*(m>>2) + 4*(c&1) + (m&3) + 32*(c>>1).
struct TileRegs { f32x4_t k[4]; float v[16]; float m; };

__global__ __launch_bounds__(256) void attn_kernel(
        const float* __restrict__ Q, const float* __restrict__ K,
        const float* __restrict__ V, const float* __restrict__ mom,
        const float* __restrict__ alpha_trend, float* __restrict__ out) {
    __shared__ __align__(16) bf16_t Ks[2][64][72];   // [p(s)][e], double-buffered
    __shared__ __align__(16) bf16_t Vt[2][64][72];   // [d][s], XOR-swizzled cols
    __shared__ __align__(16) float moms[2][64];

    const int bid  = blockIdx.x;
    const int bh   = bid & 31;
    const int qt   = 31 - (bid >> 5);       // heavy diagonals first
    const int h    = bh & 15;
    const int b    = bh >> 4;
    const int q0   = qt << 6;
    const int tid  = threadIdx.x;
    const int wave = tid >> 6;
    const int lane = tid & 63;
    const int lrow = lane & 15;
    const int lgrp = lane >> 4;

    const float c1      = 0.18033688f;      // 0.125 * log2(e)
    const float ascale2 = alpha_trend[h] * c1;
    const size_t bl     = (size_t)b * L_;
    const int qw0       = q0 + wave * 16;

    const float* Kb   = K + (bl * H_ + h) * E_;
    const float* Vb   = V + (bl * H_ + h) * D_;
    const float* momp = mom + bl;

    // staging thread mapping
    const int krow = tid >> 4;              // K source row (mod 16)
    const int ke0  = (tid & 15) << 2;
    // permuted destination row base: p(s) for s = krow + 16u is
    //   p0 + (u&1)*8 + (u>>1)*32
    const int p0   = (krow & 3) | (((krow >> 3) & 1) << 2) | (((krow >> 2) & 1) << 4);
    const int vd   = tid & 63;
    const int vsb  = tid >> 6;

    // Q fragments, prescaled by c1 (RNE, once)
    bf16x8_t a_lo, a_hi;
    {
        const float* qp = Q + ((bl + qw0 + lrow) * H_ + h) * E_ + lgrp * 8;
        f32x4_t v0 = *(const f32x4_t*)(qp);
        f32x4_t v1 = *(const f32x4_t*)(qp + 4);
        f32x4_t v2 = *(const f32x4_t*)(qp + 32);
        f32x4_t v3 = *(const f32x4_t*)(qp + 36);
        #pragma unroll
        for (int k = 0; k < 4; ++k) {
            a_lo[k]     = to_bf16(v0[k] * c1);
            a_lo[4 + k] = to_bf16(v1[k] * c1);
            a_hi[k]     = to_bf16(v2[k] * c1);
            a_hi[4 + k] = to_bf16(v3[k] * c1);
        }
    }
    const float mq = momp[qw0 + lrow];      // lane-local q momentum

    f32x4_t Oacc[4];
    #pragma unroll
    for (int c = 0; c < 4; ++c) Oacc[c] = (f32x4_t){0.f, 0.f, 0.f, 0.f};
    float rowsum = 0.f;

    // prologue: preload tile 0 into registers
    TileRegs tr;
    {
        #pragma unroll
        for (int u = 0; u < 4; ++u)
            tr.k[u] = *(const f32x4_t*)&Kb[(krow + u * 16) * (H_ * E_) + ke0];
        #pragma unroll
        for (int j = 0; j < 16; ++j)
            tr.v[j] = Vb[(vsb * 16 + j) * (H_ * D_) + vd];
        tr.m = (tid < 64) ? momp[tid] : 0.f;
    }

    char* const vtbase = (char*)Vt;
    const int vswz = ((vd >> 3) & 7) << 4;   // write-side swizzle for row vd

    for (int st = 0; st <= qt; ++st) {
        const int buf = st & 1;
        bf16_t (*Ksb)[72] = Ks[buf];
        char* vtb = vtbase + buf * (64 * 144);

        // registers -> LDS (bf16 packed). K rows go to permuted positions.
        #pragma unroll
        for (int u = 0; u < 4; ++u) {
            uint2 p;
            p.x = bpack(tr.k[u][1], tr.k[u][0]);
            p.y = bpack(tr.k[u][3], tr.k[u][2]);
            int pr = p0 + (u & 1) * 8 + (u >> 1) * 32;
            *(uint2*)&Ksb[pr][ke0] = p;
        }
        // V transposed, XOR-swizzled on row bits >=3 (colliding lanes are
        // delta-row 8 at stride 144B -> spread them across 16B slots)
        #pragma unroll
        for (int u = 0; u < 4; ++u) {
            uint2 p;
            p.x = bpack(tr.v[u * 4 + 1], tr.v[u * 4 + 0]);
            p.y = bpack(tr.v[u * 4 + 3], tr.v[u * 4 + 2]);
            int boff = (vsb * 32 + u * 8) ^ vswz;
            *(uint2*)(vtb + vd * 144 + boff) = p;
        }
        if (tid < 64) moms[buf][tid] = tr.m;
        __syncthreads();   // single barrier per step (double-buffered LDS)

        // issue next tile's global loads (latency hidden behind compute)
        if (st < qt) {
            const int s0n = (st + 1) << 6;
            #pragma unroll
            for (int u = 0; u < 4; ++u)
                tr.k[u] = *(const f32x4_t*)&Kb[(s0n + krow + u * 16) * (H_ * E_) + ke0];
            #pragma unroll
            for (int j = 0; j < 16; ++j)
                tr.v[j] = Vb[(s0n + vsb * 16 + j) * (H_ * D_) + vd];
            tr.m = (tid < 64) ? momp[s0n + tid] : 0.f;
        }

        // S^T = K Q^T (swapped operands; log2 domain via Q prescale)
        // lane holds S[q=qw0+lrow][s = 8*lgrp + 4*(c&1) + r + 32*(c>>1)]
        f32x4_t Sacc[4];
        #pragma unroll
        for (int c = 0; c < 4; ++c) Sacc[c] = (f32x4_t){0.f, 0.f, 0.f, 0.f};
        #pragma unroll
        for (int c = 0; c < 4; ++c) {
            bf16x8_t k_lo = *(const bf16x8_t*)&Ksb[c * 16 + lrow][lgrp * 8];
            bf16x8_t k_hi = *(const bf16x8_t*)&Ksb[c * 16 + lrow][32 + lgrp * 8];
            Sacc[c] = __builtin_amdgcn_mfma_f32_16x16x32_bf16(k_lo, a_lo, Sacc[c], 0, 0, 0);
            Sacc[c] = __builtin_amdgcn_mfma_f32_16x16x32_bf16(k_hi, a_hi, Sacc[c], 0, 0, 0);
        }

        // P = exp2(S - ascale2*|dm|), no max subtraction needed
        float rowe[4][4];
        #pragma unroll
        for (int c = 0; c < 4; ++c) {
            const int sb = lgrp * 8 + ((c & 1) << 2) + ((c >> 1) << 5);
            f32x4_t ms4 = *(const f32x4_t*)&moms[buf][sb];   // 4 consecutive s
            #pragma unroll
            for (int r = 0; r < 4; ++r) {
                float arg = Sacc[c][r] - ascale2 * fabsf(mq - ms4[r]);
                rowe[c][r] = __builtin_amdgcn_exp2f(arg);
            }
        }
        if (st == qt) {   // causal mask on diagonal macro-tile
            const int qg = qw0 + lrow;
            const int s0 = st << 6;
            #pragma unroll
            for (int c = 0; c < 4; ++c) {
                const int sg0 = s0 + lgrp * 8 + ((c & 1) << 2) + ((c >> 1) << 5);
                #pragma unroll
                for (int r = 0; r < 4; ++r)
                    if (sg0 + r > qg) rowe[c][r] = 0.f;
            }
        }
        #pragma unroll
        for (int c = 0; c < 4; ++c)
            rowsum += (rowe[c][0] + rowe[c][1]) + (rowe[c][2] + rowe[c][3]);

        // O += P V : P fragments are already lane-local, just pack to bf16
        #pragma unroll
        for (int hh = 0; hh < 2; ++hh) {
            union { unsigned u[4]; bf16x8_t v; } pa;
            pa.u[0] = bpack(rowe[2 * hh][1],     rowe[2 * hh][0]);
            pa.u[1] = bpack(rowe[2 * hh][3],     rowe[2 * hh][2]);
            pa.u[2] = bpack(rowe[2 * hh + 1][1], rowe[2 * hh + 1][0]);
            pa.u[3] = bpack(rowe[2 * hh + 1][3], rowe[2 * hh + 1][2]);
            #pragma unroll
            for (int c2 = 0; c2 < 4; ++c2) {
                const int row = c2 * 16 + lrow;
                int boff = (hh * 64 + lgrp * 16) ^ (((row >> 3) & 7) << 4);
                bf16x8_t bv = *(const bf16x8_t*)(vtb + row * 144 + boff);
                Oacc[c2] = __builtin_amdgcn_mfma_f32_16x16x32_bf16(pa.v, bv, Oacc[c2], 0, 0, 0);
            }
        }
    }

    // epilogue: full row sums via 2 shuffles, fetch per-r sum, normalize, store
    float rs = rowsum;
    rs += __shfl_xor(rs, 16);
    rs += __shfl_xor(rs, 32);
    // every lane now has the full sum for q-row = its lrow; Oacc rows are
    // q = qw0 + lgrp*4 + r, so pull the matching sum from lane lgrp*4+r.
    #pragma unroll
    for (int r = 0; r < 4; ++r) {
        float inv = 1.f / __shfl(rs, lgrp * 4 + r);
        size_t orow = ((bl + qw0 + lgrp * 4 + r) * H_ + h) * D_;
        #pragma unroll
        for (int c = 0; c < 4; ++c)
            out[orow + c * 16 + lrow] = Oacc[c][r] * inv;
    }
}

extern "C" void kernel_launch(void* const* d_in, const int* in_sizes, int n_in,
                              void* d_out, int out_size, void* d_ws, size_t ws_size,
                              hipStream_t stream) {
    const float* Q     = (const float*)d_in[0];
    const float* K     = (const float*)d_in[1];
    const float* V     = (const float*)d_in[2];
    const float* raw   = (const float*)d_in[3];
    const float* w1    = (const float*)d_in[4];
    const float* b1    = (const float*)d_in[5];
    const float* w2    = (const float*)d_in[6];
    const float* b2    = (const float*)d_in[7];
    const float* alpha = (const float*)d_in[8];
    float* out = (float*)d_out;

    float* fused = (float*)d_ws;                  // B*L floats
    float* mom   = fused + B_ * L_;               // B*L floats
    bf16_t* w1t  = (bf16_t*)(mom + B_ * L_);      // 256*512 bf16 (256 KB)

    transpose_w1_kernel<<<DH_, 256, 0, stream>>>(w1, w1t);
    mlp_kernel<<<B_ * L_ / 16, 256, 0, stream>>>(raw, w1t, b1, w2, b2, fused);
    momentum_kernel<<<(B_ * L_ + 255) / 256, 256, 0, stream>>>(fused, mom);
    attn_kernel<<<B_ * H_ * (L_ / 64), 256, 0, stream>>>(Q, K, V, mom, alpha, out);
}